// Round 4
// baseline (116.563 us; speedup 1.0000x reference)
//
#include <hip/hip_runtime.h>

// out[b, p] = sum_s prob[b,s] * param[p, idx[b,s]]
//   param: (512*2048, 64) fp32 = 256 MiB ; out: (64, 512*2048) fp32 = 256 MiB
// Streaming floor ~= 537 MB / 6.29 TB/s (measured R+W copy ceiling) ~= 85 us.
//
// Round 4: wave-autonomous, ZERO barriers in the main loop.
//   - each wave owns a private 8 KiB LDS region (32 pos x 64 banks) and 8
//     contiguous tiles; same-wave LDS ops are in-order -> no __syncthreads,
//     no vmcnt(0) barrier drains, compiler emits counted waits.
//   - T14 pipeline: issue next tile's global loads (-> regs) before gathering
//     the current tile; loads/stores interleave continuously per wave.
//   - LDS layout bank-major + XOR swizzle: word(k,p) = k*32 + (p ^ ((k>>2&7)<<2))
//     staging writes: exactly 2 lanes/bank (free); gather ds_read_b128:
//     uniform 8 accesses/bank = the 1KiB-per-wave minimum.

#define NPOS   (512 * 2048)
#define NBANK  64
#define NBATCH 64
#define WTILE  32
#define NTILES (NPOS / WTILE)          // 32768
#define NBLK   2048
#define TPERW  (NTILES / (NBLK * 2))   // 8 tiles per wave

typedef float f32x4 __attribute__((ext_vector_type(4)));
typedef int   i32x4 __attribute__((ext_vector_type(4)));

__global__ __launch_bounds__(128, 4) void vparam_kernel(
    const float* __restrict__ param,
    const int*   __restrict__ sel,
    const float* __restrict__ prob,
    float*       __restrict__ out)
{
    __shared__ float Ltile[2][NBANK * WTILE];   // 2 waves x 8 KiB
    __shared__ i32x4 selL[NBATCH];              // 1 KiB
    __shared__ f32x4 probL[NBATCH];             // 1 KiB

    const int tid  = threadIdx.x;
    const int lane = tid & 63;

    // one-time sel/prob staging (the only barrier in the kernel)
    if (tid < NBATCH) selL[tid]          = ((const i32x4*)sel)[tid];
    else              probL[tid - NBATCH] = ((const f32x4*)prob)[tid - NBATCH];
    __syncthreads();

    float* __restrict__ L = Ltile[tid >> 6];

    const int g     = lane >> 3;               // batch sub-group 0..7
    const int pw    = (lane & 7) << 2;         // lane's 4 positions (words)
    const int fl    = (lane & 7) << 2;         // staging swizzle (= f(k) for k>>2 = lane&15)
    const int sp    = lane >> 4;               // staged p low bits
    const int sbase = ((lane & 15) << 2) * WTILE;  // first bank row offset

    const int wave_id = blockIdx.x * 2 + (tid >> 6);
    const int t0      = wave_id * TPERW;       // 8 contiguous tiles per wave

#define LOADT(R, T) do {                                                      \
    const f32x4* gg = (const f32x4*)(param + (size_t)(T) * (WTILE * NBANK));  \
    _Pragma("unroll")                                                         \
    for (int i = 0; i < 8; ++i)                                               \
        R[i] = __builtin_nontemporal_load(&gg[i * 64 + lane]);                \
} while (0)

#define BODY(RC, RN, T, PF) do {                                              \
    /* stage regs -> LDS (bank-major, swizzled; 2 lanes/bank = free) */       \
    _Pragma("unroll")                                                         \
    for (int i = 0; i < 8; ++i) {                                             \
        int a = sbase + ((4 * i + sp) ^ fl);                                  \
        L[a]             = RC[i][0];                                          \
        L[a + WTILE]     = RC[i][1];                                          \
        L[a + 2 * WTILE] = RC[i][2];                                          \
        L[a + 3 * WTILE] = RC[i][3];                                          \
    }                                                                         \
    if (PF) LOADT(RN, (T) + 1);  /* prefetch hides under gather below */      \
    _Pragma("unroll")                                                         \
    for (int s = 0; s < 8; ++s) {                                             \
        int b = (s << 3) + g;                                                 \
        i32x4 iv = selL[b];                                                   \
        f32x4 wv = probL[b];                                                  \
        f32x4 a0 = *(const f32x4*)&L[iv.x * WTILE + (pw ^ (((iv.x >> 2) & 7) << 2))]; \
        f32x4 a1 = *(const f32x4*)&L[iv.y * WTILE + (pw ^ (((iv.y >> 2) & 7) << 2))]; \
        f32x4 a2 = *(const f32x4*)&L[iv.z * WTILE + (pw ^ (((iv.z >> 2) & 7) << 2))]; \
        f32x4 a3 = *(const f32x4*)&L[iv.w * WTILE + (pw ^ (((iv.w >> 2) & 7) << 2))]; \
        f32x4 acc = a0 * wv.x + a1 * wv.y + a2 * wv.z + a3 * wv.w;            \
        __builtin_nontemporal_store(acc,                                      \
            (f32x4*)(out + (size_t)b * NPOS + (size_t)(T) * WTILE + pw));     \
    }                                                                         \
} while (0)

    f32x4 rA[8], rB[8];
    LOADT(rA, t0);
    #pragma unroll
    for (int tt = 0; tt < TPERW; tt += 2) {     // fully unrolled: PF is constant
        BODY(rA, rB, t0 + tt,     1);
        BODY(rB, rA, t0 + tt + 1, (tt + 2 < TPERW));
    }
#undef LOADT
#undef BODY
}

extern "C" void kernel_launch(void* const* d_in, const int* in_sizes, int n_in,
                              void* d_out, int out_size, void* d_ws, size_t ws_size,
                              hipStream_t stream) {
    const float* param = (const float*)d_in[0];
    const int*   sel   = (const int*)d_in[1];
    const float* prob  = (const float*)d_in[2];
    float*       out   = (float*)d_out;

    vparam_kernel<<<dim3(NBLK), dim3(128), 0, stream>>>(param, sel, prob, out);
}